// Round 4
// baseline (136.656 us; speedup 1.0000x reference)
//
#include <hip/hip_runtime.h>
#include <stdint.h>

// KANLinear: y = silu(x) @ W_b^T + einsum('big,oig->bo', bases(x), W_s * scaler)
// R3: Act stored chunk-tiled Act2[chunk=k/8][row][8] bf16 so GEMM A-fragments are
// direct global->VGPR dwordx4 loads (no LDS for A). LDS = B-only ring-3 (48KB),
// B-frag register reuse, 1 barrier/K-tile, 4-wave blocks, 2 blocks/CU.

#define IN_F   512
#define OUT_F  512
#define KDIM   4608
#define BATCH  16384
#define CH_STRIDE (BATCH * 8)          // elems per chunk slab = 131072

#define BM 128
#define BN 128
#define BK 64
#define NT (KDIM / BK)                 // 72
#define B_ELEMS (BN * BK)              // 8192 elems = 16 KiB

typedef unsigned short u16;
typedef short s16x8 __attribute__((ext_vector_type(8)));
typedef float f32x4 __attribute__((ext_vector_type(4)));

__device__ __forceinline__ u16 f2bf(float f) {
    uint32_t u = __builtin_bit_cast(uint32_t, f);
    uint32_t r = (u + 0x7FFFu + ((u >> 16) & 1u)) >> 16;   // RNE
    return (u16)r;
}

__device__ __forceinline__ float cleanx(float v) {
    if (v != v) v = 0.0f;                          // nan -> 0
    v = fminf(fmaxf(v, -6.0f), 6.0f);              // also folds +-inf
    return fminf(fmaxf(v, -1.1f), 1.1f);           // grid clamp
}

// ---------------- weight prep: Wc[o][k] bf16 (pre-XOR-swizzled rows) -----------
__global__ void prep_w_kernel(const float* __restrict__ bw,
                              const float* __restrict__ sw,
                              const float* __restrict__ sc,
                              u16* __restrict__ Wc) {
    int idx = blockIdx.x * 256 + threadIdx.x;      // (o,i), 512*512 threads
    int o = idx >> 9;
    int i = idx & 511;
    int swz = o & 7;
    Wc[(size_t)o * KDIM + (i ^ (swz << 3))] = f2bf(bw[idx]);
    float s = sc[idx];
    const float4* sp = reinterpret_cast<const float4*>(sw + (size_t)idx * 8);
    float4 a = sp[0];
    float4 b = sp[1];
    union { u16 us[8]; uint4 v; } pk;
    pk.us[0] = f2bf(a.x * s); pk.us[1] = f2bf(a.y * s);
    pk.us[2] = f2bf(a.z * s); pk.us[3] = f2bf(a.w * s);
    pk.us[4] = f2bf(b.x * s); pk.us[5] = f2bf(b.y * s);
    pk.us[6] = f2bf(b.z * s); pk.us[7] = f2bf(b.w * s);
    *reinterpret_cast<uint4*>(Wc + (size_t)o * KDIM + IN_F + (size_t)(i ^ swz) * 8) = pk.v;
}

// ---------------- silu prep: chunks 0..63, Act2[c][b][e] = silu(x[b][c*8+e]) ---
__global__ void prep_silu_kernel(const float* __restrict__ x,
                                 u16* __restrict__ Act2) {
    int idx = blockIdx.x * 256 + threadIdx.x;      // BATCH*64 threads
    int b = idx & 16383;
    int c = idx >> 14;                             // 0..63
    const float4* xp = reinterpret_cast<const float4*>(x + (size_t)b * 512 + c * 8);
    float4 v0 = xp[0], v1 = xp[1];
    float vv[8] = {v0.x, v0.y, v0.z, v0.w, v1.x, v1.y, v1.z, v1.w};
    union { u16 us[8]; uint4 q; } pk;
    #pragma unroll
    for (int e = 0; e < 8; ++e) {
        float v = cleanx(vv[e]);
        pk.us[e] = f2bf(v / (1.0f + __expf(-v)));
    }
    *reinterpret_cast<uint4*>(Act2 + (size_t)c * CH_STRIDE + (size_t)b * 8) = pk.q;
}

// ---------------- bases prep: chunk 64+i holds the 8 bases of input i ----------
// Uniform knots t_j = -2.2 + 0.4*j; x in [t_2, t_9) after clipping.
__global__ void prep_bases_kernel(const float* __restrict__ x,
                                  u16* __restrict__ Act2) {
    int idx = blockIdx.x * 256 + threadIdx.x;      // BATCH*IN_F threads
    int b = idx & 16383;
    int i = idx >> 14;                             // 0..511
    float v = cleanx(x[(size_t)b * 512 + i]);

    float t = (v + 2.2f) * 2.5f;                   // (v - t0)/h, h=0.4
    int m = (int)floorf(t);
    m = min(max(m, 2), 8);
    float u = t - (float)m;
    float u2 = u * u;
    float u3 = u2 * u;
    float p0 = u3 * (1.0f / 6.0f);                              // g = m
    float p1 = (1.0f + 3.0f * u + 3.0f * u2 - 3.0f * u3) * (1.0f / 6.0f); // g = m-1
    float p2 = (4.0f - 6.0f * u2 + 3.0f * u3) * (1.0f / 6.0f);  // g = m-2
    float w1 = 1.0f - u;
    float p3 = w1 * w1 * w1 * (1.0f / 6.0f);                    // g = m-3

    union { u16 us[8]; uint4 q; } pk;
    #pragma unroll
    for (int g = 0; g < 8; ++g) {
        int j = m - g;
        float r = 0.0f;
        r = (j == 0) ? p0 : r;
        r = (j == 1) ? p1 : r;
        r = (j == 2) ? p2 : r;
        r = (j == 3) ? p3 : r;
        pk.us[g] = f2bf(r);
    }
    *reinterpret_cast<uint4*>(Act2 + (size_t)(64 + i) * CH_STRIDE + (size_t)b * 8) = pk.q;
}

// ---------------- GEMM: C(16384x512) = Act(16384x4608) @ Wc(512x4608)^T --------
__global__ __launch_bounds__(256, 2) void gemm_kernel(const u16* __restrict__ Act2,
                                                      const u16* __restrict__ Bw,
                                                      float* __restrict__ C) {
    __shared__ u16 Bs[3 * B_ELEMS];                // 48 KiB, B-only ring-3

    const int tid  = threadIdx.x;
    const int w    = tid >> 6;
    const int lane = tid & 63;

    // XCD-bijective swizzle, nwg = 512 (%8 == 0); 4 N-siblings adjacent per XCD
    const int bid = blockIdx.x;
    const int wg  = (bid & 7) * 64 + (bid >> 3);
    const int bm0 = (wg >> 2) * BM;
    const int bn0 = (wg & 3) * BN;

    const int wr = (w >> 1) * 64;       // 2 M-waves
    const int wc = (w & 1) * 64;        // 2 N-waves

    const int rA   = lane & 15;
    const int sK   = (rA & 7) << 3;     // ds_read column swizzle (elements)
    const int kgrp = (lane >> 4) * 8;

    f32x4 acc[4][4] = {};

    // A base: chunk (lane>>4), row bm0+wr+rA; per (kt,kk,m) add offsets
    const u16* Abase = Act2 + (size_t)(lane >> 4) * CH_STRIDE
                            + (size_t)(bm0 + wr + rA) * 8;

    auto stageB = [&](u16* dst, int kt) {
        #pragma unroll
        for (int c = 0; c < 4; ++c) {
            int off = tid * 8 + c * 2048;
            int row = off >> 6, col = off & 63;
            const u16* g = Bw + (size_t)(bn0 + row) * KDIM + kt * BK + col;
            __builtin_amdgcn_global_load_lds(
                (const __attribute__((address_space(1))) uint32_t*)g,
                (__attribute__((address_space(3))) uint32_t*)(dst + off), 16, 0, 0);
        }
    };
    auto loadA = [&](s16x8 (&af)[4][2], int kt) {
        const u16* p = Abase + (size_t)kt * (8 * CH_STRIDE);
        #pragma unroll
        for (int kk = 0; kk < 2; ++kk)
            #pragma unroll
            for (int m = 0; m < 4; ++m)
                af[m][kk] = *reinterpret_cast<const s16x8*>(
                    p + (size_t)kk * (4 * CH_STRIDE) + m * 128);
    };

    s16x8 afE[4][2], afO[4][2];

    // prologue: B(0), B(1) staged; A(0) in regs. Drain B(0) (leave B(1)+A(0)=12).
    stageB(Bs, 0);
    stageB(Bs + B_ELEMS, 1);
    loadA(afE, 0);
    asm volatile("s_waitcnt vmcnt(12)" ::: "memory");

    int rb = 0, sb = 2;
    auto tile = [&](s16x8 (&cur)[4][2], s16x8 (&nxt)[4][2], int t) {
        __builtin_amdgcn_s_barrier();
        // issue order matters: stageB first, loadA second -> the compiler's
        // pre-MFMA vmcnt for A(t) also drains B(t+1) (issued earlier at t-1).
        if (t + 2 < NT) stageB(Bs + sb * B_ELEMS, t + 2);
        sb = (sb == 2) ? 0 : sb + 1;
        if (t + 1 < NT) loadA(nxt, t + 1);
        u16* bufR = Bs + rb * B_ELEMS;
        rb = (rb == 2) ? 0 : rb + 1;
        s16x8 bf[2][4];
        #pragma unroll
        for (int kk = 0; kk < 2; ++kk)
            #pragma unroll
            for (int n = 0; n < 4; ++n)
                bf[kk][n] = *reinterpret_cast<const s16x8*>(
                    &bufR[(wc + n * 16 + rA) * BK + ((kk * 32 + kgrp) ^ sK)]);
        __builtin_amdgcn_s_setprio(1);
        #pragma unroll
        for (int kk = 0; kk < 2; ++kk)
            #pragma unroll
            for (int m = 0; m < 4; ++m)
                #pragma unroll
                for (int n = 0; n < 4; ++n)
                    acc[m][n] = __builtin_amdgcn_mfma_f32_16x16x32_bf16(
                        cur[m][kk], bf[kk][n], acc[m][n], 0, 0, 0);
        __builtin_amdgcn_s_setprio(0);
    };

    for (int t = 0; t < NT; t += 2) {
        tile(afE, afO, t);
        tile(afO, afE, t + 1);
    }

    // epilogue: C/D layout col = lane&15, row = (lane>>4)*4 + reg
    const int rq = lane >> 4;
    const int cn = lane & 15;
    #pragma unroll
    for (int am = 0; am < 4; ++am) {
        #pragma unroll
        for (int an = 0; an < 4; ++an) {
            const int row0 = bm0 + wr + am * 16 + rq * 4;
            const int col  = bn0 + wc + an * 16 + cn;
            float* cp = C + (size_t)row0 * OUT_F + col;
            cp[0 * OUT_F] = acc[am][an][0];
            cp[1 * OUT_F] = acc[am][an][1];
            cp[2 * OUT_F] = acc[am][an][2];
            cp[3 * OUT_F] = acc[am][an][3];
        }
    }
}

extern "C" void kernel_launch(void* const* d_in, const int* in_sizes, int n_in,
                              void* d_out, int out_size, void* d_ws, size_t ws_size,
                              hipStream_t stream) {
    const float* x  = (const float*)d_in[0];
    const float* bw = (const float*)d_in[1];
    const float* sw = (const float*)d_in[2];
    const float* sc = (const float*)d_in[3];
    // d_in[4] (grid) unused: uniform knots by construction

    u16* Wc   = (u16*)d_ws;                        // 512*4608*2   = 4.7 MB
    u16* Act2 = Wc + (size_t)OUT_F * KDIM;         // 576*16384*8*2 = 151 MB

    prep_w_kernel<<<(OUT_F * IN_F) / 256, 256, 0, stream>>>(bw, sw, sc, Wc);
    prep_silu_kernel<<<(BATCH * 64) / 256, 256, 0, stream>>>(x, Act2);
    prep_bases_kernel<<<(BATCH * IN_F) / 256, 256, 0, stream>>>(x, Act2);
    gemm_kernel<<<(BATCH / BM) * (OUT_F / BN), 256, 0, stream>>>(Act2, Wc, (float*)d_out);
}

// Round 5
// 110.788 us; speedup vs baseline: 1.2335x; 1.2335x over previous
//
#include <hip/hip_runtime.h>
#include <stdint.h>

// KANLinear: y = silu(x) @ W_b^T + einsum('big,oig->bo', bases(x), W_s * scaler)
// Act = [silu(x) | bases] (B x 4608) bf16, Wc = [W_b | W_s*scaler] (512 x 4608) bf16,
// both pre-XOR-swizzled per 64-elem K-group; one bf16 MFMA GEMM.
// R4: BM128xBN128 / 4 waves / double-buffered 64KB LDS -> 2 blocks/CU (two
// independent barrier groups overlap each other's stalls), counted vmcnt(8),
// one 32-MFMA cluster per K-tile, setprio(1) around the cluster.

#define IN_F   512
#define OUT_F  512
#define KDIM   4608
#define BATCH  16384

#define BM 128
#define BN 128
#define BK 64
#define NT (KDIM / BK)                 // 72
#define A_ELEMS (BM * BK)              // 8192 elems
#define B_ELEMS (BN * BK)              // 8192 elems
#define TILE_ELEMS (A_ELEMS + B_ELEMS) // 16384 elems = 32 KiB
#define LDS_BYTES (2 * TILE_ELEMS * 2) // 65536 B

typedef unsigned short u16;
typedef short s16x8 __attribute__((ext_vector_type(8)));
typedef float f32x4 __attribute__((ext_vector_type(4)));

__device__ __forceinline__ u16 f2bf(float f) {
    uint32_t u = __builtin_bit_cast(uint32_t, f);
    uint32_t r = (u + 0x7FFFu + ((u >> 16) & 1u)) >> 16;   // RNE
    return (u16)r;
}

// ---------------- weight prep: Wc[o][k] bf16 (pre-swizzled) --------------------
__global__ void prep_w_kernel(const float* __restrict__ bw,
                              const float* __restrict__ sw,
                              const float* __restrict__ sc,
                              u16* __restrict__ Wc) {
    int idx = blockIdx.x * 256 + threadIdx.x;      // (o,i), 512*512 threads
    int o = idx >> 9;
    int i = idx & 511;
    int swz = o & 7;
    Wc[(size_t)o * KDIM + (i ^ (swz << 3))] = f2bf(bw[idx]);
    float s = sc[idx];
    const float4* sp = reinterpret_cast<const float4*>(sw + (size_t)idx * 8);
    float4 a = sp[0];
    float4 b = sp[1];
    union { u16 us[8]; uint4 v; } pk;
    pk.us[0] = f2bf(a.x * s); pk.us[1] = f2bf(a.y * s);
    pk.us[2] = f2bf(a.z * s); pk.us[3] = f2bf(a.w * s);
    pk.us[4] = f2bf(b.x * s); pk.us[5] = f2bf(b.y * s);
    pk.us[6] = f2bf(b.z * s); pk.us[7] = f2bf(b.w * s);
    *reinterpret_cast<uint4*>(Wc + (size_t)o * KDIM + IN_F + (size_t)(i ^ swz) * 8) = pk.v;
}

// ---------------- activation prep: Act[b][*] bf16 (pre-swizzled) ---------------
// Uniform knots t_j = -2.2 + 0.4*j; x in [t_2, t_9) after clipping.
__global__ void prep_x_kernel(const float* __restrict__ x,
                              u16* __restrict__ Act) {
    int idx = blockIdx.x * 256 + threadIdx.x;      // (b,i), BATCH*IN_F threads
    int b = idx >> 9;
    int i = idx & 511;
    int swz = b & 7;
    float v = x[idx];
    if (v != v) v = 0.0f;                          // nan -> 0
    v = fminf(fmaxf(v, -6.0f), 6.0f);              // also folds +-inf
    v = fminf(fmaxf(v, -1.1f), 1.1f);              // grid clamp
    float s = v / (1.0f + __expf(-v));
    Act[(size_t)b * KDIM + (i ^ (swz << 3))] = f2bf(s);

    float t = (v + 2.2f) * 2.5f;                   // (v - t0)/h, h=0.4
    int m = (int)floorf(t);
    m = min(max(m, 2), 8);
    float u = t - (float)m;
    float u2 = u * u;
    float u3 = u2 * u;
    float p0 = u3 * (1.0f / 6.0f);
    float p1 = (1.0f + 3.0f * u + 3.0f * u2 - 3.0f * u3) * (1.0f / 6.0f);
    float p2 = (4.0f - 6.0f * u2 + 3.0f * u3) * (1.0f / 6.0f);
    float w1 = 1.0f - u;
    float p3 = w1 * w1 * w1 * (1.0f / 6.0f);

    union { u16 us[8]; uint4 v4; } pk;
    #pragma unroll
    for (int g = 0; g < 8; ++g) {
        int j = m - g;
        float r = 0.0f;
        r = (j == 0) ? p0 : r;
        r = (j == 1) ? p1 : r;
        r = (j == 2) ? p2 : r;
        r = (j == 3) ? p3 : r;
        pk.us[g] = f2bf(r);
    }
    *reinterpret_cast<uint4*>(Act + (size_t)b * KDIM + IN_F + (size_t)(i ^ swz) * 8) = pk.v4;
}

// ---------------- GEMM: C(16384x512) = Act(16384x4608) @ Wc(512x4608)^T --------
extern __shared__ u16 Sm[];

__global__ __launch_bounds__(256, 2) void gemm_kernel(const u16* __restrict__ A,
                                                      const u16* __restrict__ Bw,
                                                      float* __restrict__ C) {
    const int tid  = threadIdx.x;
    const int w    = tid >> 6;
    const int lane = tid & 63;

    // XCD-bijective swizzle, nwg = 512 (%8 == 0); 4 N-siblings adjacent per XCD
    const int bid = blockIdx.x;
    const int wg  = (bid & 7) * 64 + (bid >> 3);
    const int bm0 = (wg >> 2) * BM;
    const int bn0 = (wg & 3) * BN;

    const int wr = (w >> 1) * 64;       // 2 M-waves
    const int wc = (w & 1) * 64;        // 2 N-waves

    const int rA   = lane & 15;
    const int sK   = (rA & 7) << 3;     // ds_read column swizzle (elements)
    const int kgrp = (lane >> 4) * 8;

    f32x4 acc[4][4] = {};

    auto stage = [&](u16* dst, int kt) {
        #pragma unroll
        for (int c = 0; c < 4; ++c) {
            int off = tid * 8 + c * 2048;
            int row = off >> 6, col = off & 63;
            const u16* ga = A  + (size_t)(bm0 + row) * KDIM + kt * BK + col;
            const u16* gb = Bw + (size_t)(bn0 + row) * KDIM + kt * BK + col;
            __builtin_amdgcn_global_load_lds(
                (const __attribute__((address_space(1))) uint32_t*)ga,
                (__attribute__((address_space(3))) uint32_t*)(dst + off), 16, 0, 0);
            __builtin_amdgcn_global_load_lds(
                (const __attribute__((address_space(1))) uint32_t*)gb,
                (__attribute__((address_space(3))) uint32_t*)(dst + A_ELEMS + off), 16, 0, 0);
        }
    };

    stage(Sm, 0);                        // prologue

    int cur = 0;
    for (int t = 0; t < NT; ++t) {
        __builtin_amdgcn_s_barrier();    // all waves done reading buf[cur^1]
        if (t + 1 < NT) {
            stage(Sm + (cur ^ 1) * TILE_ELEMS, t + 1);
            asm volatile("s_waitcnt vmcnt(8)" ::: "memory");   // tile t landed
        } else {
            asm volatile("s_waitcnt vmcnt(0)" ::: "memory");
        }
        __builtin_amdgcn_s_barrier();    // whole tile t visible to all waves

        const u16* As_ = Sm + cur * TILE_ELEMS;
        const u16* Bs_ = As_ + A_ELEMS;

        s16x8 af[4][2], bf[2][4];
        #pragma unroll
        for (int kk = 0; kk < 2; ++kk) {
            const int kc = (kk * 32 + kgrp) ^ sK;
            #pragma unroll
            for (int m = 0; m < 4; ++m)
                af[m][kk] = *reinterpret_cast<const s16x8*>(&As_[(wr + m * 16 + rA) * BK + kc]);
            #pragma unroll
            for (int n = 0; n < 4; ++n)
                bf[kk][n] = *reinterpret_cast<const s16x8*>(&Bs_[(wc + n * 16 + rA) * BK + kc]);
        }
        __builtin_amdgcn_s_setprio(1);
        #pragma unroll
        for (int kk = 0; kk < 2; ++kk)
            #pragma unroll
            for (int m = 0; m < 4; ++m)
                #pragma unroll
                for (int n = 0; n < 4; ++n)
                    acc[m][n] = __builtin_amdgcn_mfma_f32_16x16x32_bf16(
                        af[m][kk], bf[kk][n], acc[m][n], 0, 0, 0);
        __builtin_amdgcn_s_setprio(0);
        cur ^= 1;
    }

    // epilogue: C/D layout col = lane&15, row = (lane>>4)*4 + reg
    const int rq = lane >> 4;
    const int cn = lane & 15;
    #pragma unroll
    for (int am = 0; am < 4; ++am) {
        #pragma unroll
        for (int an = 0; an < 4; ++an) {
            const int row0 = bm0 + wr + am * 16 + rq * 4;
            const int col  = bn0 + wc + an * 16 + cn;
            float* cp = C + (size_t)row0 * OUT_F + col;
            cp[0 * OUT_F] = acc[am][an][0];
            cp[1 * OUT_F] = acc[am][an][1];
            cp[2 * OUT_F] = acc[am][an][2];
            cp[3 * OUT_F] = acc[am][an][3];
        }
    }
}

extern "C" void kernel_launch(void* const* d_in, const int* in_sizes, int n_in,
                              void* d_out, int out_size, void* d_ws, size_t ws_size,
                              hipStream_t stream) {
    const float* x  = (const float*)d_in[0];
    const float* bw = (const float*)d_in[1];
    const float* sw = (const float*)d_in[2];
    const float* sc = (const float*)d_in[3];
    // d_in[4] (grid) unused: uniform knots by construction

    u16* Wc  = (u16*)d_ws;                         // 512*4608*2   = 4.7 MB
    u16* Act = Wc + (size_t)OUT_F * KDIM;          // 16384*4608*2 = 151 MB

    hipFuncSetAttribute((const void*)gemm_kernel,
                        hipFuncAttributeMaxDynamicSharedMemorySize, LDS_BYTES);

    prep_w_kernel<<<(OUT_F * IN_F) / 256, 256, 0, stream>>>(bw, sw, sc, Wc);
    prep_x_kernel<<<(BATCH * IN_F) / 256, 256, 0, stream>>>(x, Act);
    gemm_kernel<<<(BATCH / BM) * (OUT_F / BN), 256, LDS_BYTES, stream>>>(Act, Wc, (float*)d_out);
}